// Round 8
// baseline (65019.031 us; speedup 1.0000x reference)
//
#include <hip/hip_runtime.h>
#include <cmath>

#define VOCAB   4096
#define ENC_DIM 1024
#define PRED_H  640
#define JOINT_H 640
#define TMAX    128
#define MAX_SYM 30
#define NSTEPS  (TMAX*(MAX_SYM+1))   // 3968
#define NWG     256
#define NTHR    512
#define RLX __ATOMIC_RELAXED
#define AGT __HIP_MEMORY_SCOPE_AGENT

typedef unsigned long long u64;

// ws layout (bytes) — single copy, IC-resident (~21.5 KB):
//   0     : parts[256] u64 (tagged argmax entries)        [0,2048)
//   4096  : bufsT[1280] u64: h0n(640) | h1n(640) tagged   [4096,14336)
//   14336 : hidT[640] u64 tagged                          [14336,19456)
// tagged word = (tag u32 << 32) | f32 bits. tag = s+1 (>=1; 0 = unwritten)

__device__ __forceinline__ float wave_red(float v){
  v += __shfl_xor(v, 32, 64);
  v += __shfl_xor(v, 16, 64);
  v += __shfl_xor(v,  8, 64);
  v += __shfl_xor(v,  4, 64);
  v += __shfl_xor(v,  2, 64);
  v += __shfl_xor(v,  1, 64);
  return v;
}

__device__ __forceinline__ float sigf(float x){ return 1.0f/(1.0f+expf(-x)); }

__device__ __forceinline__ void tstore(u64* p, float v, unsigned tag){
  __hip_atomic_store(p, ((u64)tag<<32) | (u64)__float_as_uint(v), RLX, AGT);
}

// 5-element batched poll: issue all 5 loads back-to-back (5 outstanding ->
// ~1 RTT per round), re-issue the whole batch until every tag matches.
// pt in [0,128): elements [pt*5, pt*5+5).
__device__ __forceinline__ void poll5(u64* src, float* dst, unsigned tag, int pt){
  u64* p = src + pt*5;
  u64 a0,a1,a2,a3,a4;
  for(;;){
    a0 = __hip_atomic_load(p+0, RLX, AGT);
    a1 = __hip_atomic_load(p+1, RLX, AGT);
    a2 = __hip_atomic_load(p+2, RLX, AGT);
    a3 = __hip_atomic_load(p+3, RLX, AGT);
    a4 = __hip_atomic_load(p+4, RLX, AGT);
    bool ok = ((unsigned)(a0>>32) == tag) & ((unsigned)(a1>>32) == tag)
            & ((unsigned)(a2>>32) == tag) & ((unsigned)(a3>>32) == tag)
            & ((unsigned)(a4>>32) == tag);
    if (ok) break;
    __builtin_amdgcn_s_sleep(1);
  }
  float* d = dst + pt*5;
  d[0] = __uint_as_float((unsigned)a0);
  d[1] = __uint_as_float((unsigned)a1);
  d[2] = __uint_as_float((unsigned)a2);
  d[3] = __uint_as_float((unsigned)a3);
  d[4] = __uint_as_float((unsigned)a4);
}

// argmax entry: key(32b order-preserving) << 24 | (tag&0xFFF)<<12 | (4095-r)
__device__ __forceinline__ u64 mkentry(float lg, int r, unsigned ep){
  unsigned u = __float_as_uint(lg);
  u = (u & 0x80000000u) ? ~u : (u | 0x80000000u);
  return ((u64)u<<24) | ((u64)(ep&0xFFFu)<<12) | (u64)(4095 - r);
}

__global__ void init_ws(unsigned* ws){
  for (int i = threadIdx.x; i < 8192; i += 256) ws[i] = 0u;   // 32 KB
}

__global__ __launch_bounds__(NTHR, 2)
void rnnt_decode(const float* __restrict__ enc,
                 const int*   __restrict__ outlen_p,
                 const float* __restrict__ emb,
                 const float* __restrict__ Wih0, const float* __restrict__ Whh0, const float* __restrict__ b0,
                 const float* __restrict__ Wih1, const float* __restrict__ Whh1, const float* __restrict__ b1,
                 const float* __restrict__ Wj1,  const float* __restrict__ bj1,
                 const float* __restrict__ Wj2,  const float* __restrict__ bj2,
                 float* __restrict__ out,
                 u64* __restrict__ parts,        // [256]
                 u64* __restrict__ bufsT,        // [2*PRED_H]
                 u64* __restrict__ hidT)         // [JOINT_H]
{
  const int wg = blockIdx.x, tid = threadIdx.x;
  const int wave = tid >> 6, lane = tid & 63;
  const int timesteps = outlen_p[0];

  __shared__ float xa[PRED_H];
  __shared__ float xsh[ENC_DIM];
  __shared__ float h0buf[2][PRED_H];
  __shared__ float h1buf[2][PRED_H];
  __shared__ float hidsh[JOINT_H];
  __shared__ float zsh[4][4];
  __shared__ float zjs[8];
  __shared__ float zjs2[4];
  __shared__ float c0c[4], c1c[4], c0p[4], c1p[4];
  __shared__ u64 psh[8];
  __shared__ u64 pmx[4];

  const int jb = (wg*PRED_H)/NWG;
  const int je = ((wg+1)*PRED_H)/NWG;
  const int nj = je - jb;                 // 2 or 3

  // ---- persistent LSTM weight registers (identical mapping to R5) ----
  const int riA = wave, riB = wave + 8;
  const int gA = riA & 3, jA = riA >> 2;
  const int gB = riB & 3, jBx = riB >> 2;
  const bool hasB = (riB < 4*nj);
  const int rowA = gA*PRED_H + jb + jA;
  const int rowB = hasB ? (gB*PRED_H + jb + jBx) : 0;

  float w0xA[10], w0hA[10], w0xB[10], w0hB[10];
  float w1xA[10], w1hA[10], w1xB[10], w1hB[10];
  #pragma unroll
  for (int i = 0; i < 10; ++i){
    int c = lane + (i<<6);
    w0xA[i] = Wih0[(size_t)rowA*PRED_H + c];
    w0hA[i] = Whh0[(size_t)rowA*PRED_H + c];
    w1xA[i] = Wih1[(size_t)rowA*PRED_H + c];
    w1hA[i] = Whh1[(size_t)rowA*PRED_H + c];
    w0xB[i] = hasB ? Wih0[(size_t)rowB*PRED_H + c] : 0.f;
    w0hB[i] = hasB ? Whh0[(size_t)rowB*PRED_H + c] : 0.f;
    w1xB[i] = hasB ? Wih1[(size_t)rowB*PRED_H + c] : 0.f;
    w1hB[i] = hasB ? Whh1[(size_t)rowB*PRED_H + c] : 0.f;
  }
  const float bA0 = b0[rowA], bA1 = b1[rowA];
  const float bB0 = hasB ? b0[rowB] : 0.f, bB1 = hasB ? b1[rowB] : 0.f;

  // ---- Wj1 per-role (waves 0-3: rows jb, jb+2; waves 4-7: row jb+1) ----
  const int vt = (wave < 4) ? wave*64 + lane : (wave-4)*64 + lane;  // 0..255
  float wjf0[4], wjh0[3], wjf2[4], wjh2[3];
  {
    int r0 = (wave < 4) ? jb : jb + 1;
    #pragma unroll
    for (int i = 0; i < 4; ++i) wjf0[i] = Wj1[(size_t)r0*(ENC_DIM+PRED_H) + vt + (i<<8)];
    #pragma unroll
    for (int i = 0; i < 3; ++i){
      int c = vt + (i<<8);
      wjh0[i] = (c < PRED_H) ? Wj1[(size_t)r0*(ENC_DIM+PRED_H) + ENC_DIM + c] : 0.f;
    }
    #pragma unroll
    for (int i = 0; i < 4; ++i) wjf2[i] = 0.f;
    #pragma unroll
    for (int i = 0; i < 3; ++i) wjh2[i] = 0.f;
    if (wave < 4 && nj == 3){
      int r2 = jb + 2;
      #pragma unroll
      for (int i = 0; i < 4; ++i) wjf2[i] = Wj1[(size_t)r2*(ENC_DIM+PRED_H) + vt + (i<<8)];
      #pragma unroll
      for (int i = 0; i < 3; ++i){
        int c = vt + (i<<8);
        wjh2[i] = (c < PRED_H) ? Wj1[(size_t)r2*(ENC_DIM+PRED_H) + ENC_DIM + c] : 0.f;
      }
    }
  }
  float bjr[3];
  bjr[0] = bj1[jb]; bjr[1] = bj1[jb+1]; bjr[2] = (nj == 3) ? bj1[jb+2] : 0.f;
  float ca0 = 0.f, ca2 = 0.f;

  // ---- Wj2: 16 rows per WG, 2 per wave ----
  const int rA2 = wg*16 + wave*2, rB2 = rA2 + 1;
  float wj2A[10], wj2B[10];
  #pragma unroll
  for (int i = 0; i < 10; ++i){
    int c = lane + (i<<6);
    wj2A[i] = Wj2[(size_t)rA2*JOINT_H + c];
    wj2B[i] = Wj2[(size_t)rB2*JOINT_H + c];
  }
  const float bjA2 = bj2[rA2], bjB2 = bj2[rB2];

  for (int i = tid; i < PRED_H; i += NTHR){ h0buf[0][i] = 0.f; h1buf[0][i] = 0.f; }
  if (tid < 4){ c0c[tid] = 0.f; c1c[tid] = 0.f; }
  __syncthreads();

  int cur = 0, t = 0, sa = 0, last = -1, cnt = 0, tStaged = -1;
  bool done = false, reuse = false;

  for (int s = 0; s < NSTEPS; ++s){
    if (done){
      if (wg < 8) out[(size_t)s*VOCAB + wg*NTHR + tid] = 0.f;
      continue;
    }
    const unsigned tag = (unsigned)(s + 1);

    if (!reuse){
      // ===== A: LSTM layer 0 (inputs all LDS-local) =====
      for (int i = tid; i < PRED_H; i += NTHR)
        xa[i] = (last >= 0) ? emb[(size_t)last*PRED_H + i] : 0.f;
      __syncthreads();
      {
        float acc = 0.f;
        #pragma unroll
        for (int i = 0; i < 10; ++i) acc = fmaf(w0xA[i], xa[lane+(i<<6)], acc);
        #pragma unroll
        for (int i = 0; i < 10; ++i) acc = fmaf(w0hA[i], h0buf[cur][lane+(i<<6)], acc);
        acc = wave_red(acc);
        if (lane == 0) zsh[gA][jA] = acc + bA0;
        if (hasB){
          float a2 = 0.f;
          #pragma unroll
          for (int i = 0; i < 10; ++i) a2 = fmaf(w0xB[i], xa[lane+(i<<6)], a2);
          #pragma unroll
          for (int i = 0; i < 10; ++i) a2 = fmaf(w0hB[i], h0buf[cur][lane+(i<<6)], a2);
          a2 = wave_red(a2);
          if (lane == 0) zsh[gB][jBx] = a2 + bB0;
        }
      }
      __syncthreads();
      if (tid < nj){
        float ig = sigf(zsh[0][tid]), fg = sigf(zsh[1][tid]);
        float gg = tanhf(zsh[2][tid]), og = sigf(zsh[3][tid]);
        float c2 = fg*c0c[tid] + ig*gg;
        c0p[tid] = c2;
        tstore(&bufsT[jb+tid], og*tanhf(c2), tag);
      }
      __syncthreads();

      // ===== B: LSTM layer 1 =====
      if (wave < 2) poll5(bufsT, h0buf[cur^1], tag, tid);   // h0n, 5-deep MLP
      __syncthreads();
      {
        float acc = 0.f;
        #pragma unroll
        for (int i = 0; i < 10; ++i) acc = fmaf(w1xA[i], h0buf[cur^1][lane+(i<<6)], acc);
        #pragma unroll
        for (int i = 0; i < 10; ++i) acc = fmaf(w1hA[i], h1buf[cur][lane+(i<<6)], acc);
        acc = wave_red(acc);
        if (lane == 0) zsh[gA][jA] = acc + bA1;
        if (hasB){
          float a2 = 0.f;
          #pragma unroll
          for (int i = 0; i < 10; ++i) a2 = fmaf(w1xB[i], h0buf[cur^1][lane+(i<<6)], a2);
          #pragma unroll
          for (int i = 0; i < 10; ++i) a2 = fmaf(w1hB[i], h1buf[cur][lane+(i<<6)], a2);
          a2 = wave_red(a2);
          if (lane == 0) zsh[gB][jBx] = a2 + bB1;
        }
      }
      __syncthreads();
      if (tid < nj){
        float ig = sigf(zsh[0][tid]), fg = sigf(zsh[1][tid]);
        float gg = tanhf(zsh[2][tid]), og = sigf(zsh[3][tid]);
        float c2 = fg*c1c[tid] + ig*gg;
        c1p[tid] = c2;
        tstore(&bufsT[PRED_H+jb+tid], og*tanhf(c2), tag);
      }
    }

    // ===== C: joint hidden (single-pass, all nj rows) =====
    {
      int tcap = (t < TMAX-1) ? t : (TMAX-1);
      bool fNew = (tcap != tStaged);
      if (fNew)
        for (int i = tid; i < ENC_DIM; i += NTHR) xsh[i] = enc[(size_t)tcap*ENC_DIM + i];
      if (!reuse){
        if (wave < 2) poll5(bufsT + PRED_H, h1buf[cur^1], tag, tid);  // h1n
      }
      __syncthreads();
      if (fNew){
        float a = 0.f;
        #pragma unroll
        for (int i = 0; i < 4; ++i) a = fmaf(wjf0[i], xsh[vt+(i<<8)], a);
        ca0 = a;
        if (wave < 4 && nj == 3){
          float a2 = 0.f;
          #pragma unroll
          for (int i = 0; i < 4; ++i) a2 = fmaf(wjf2[i], xsh[vt+(i<<8)], a2);
          ca2 = a2;
        }
        tStaged = tcap;
      }
      {
        float acc = ca0;
        #pragma unroll
        for (int i = 0; i < 3; ++i){
          int c = vt + (i<<8);
          acc = fmaf(wjh0[i], h1buf[cur^1][(c < PRED_H) ? c : 0], acc);
        }
        acc = wave_red(acc);
        if (lane == 0) zjs[wave] = acc;
      }
      if (wave < 4 && nj == 3){
        float acc = ca2;
        #pragma unroll
        for (int i = 0; i < 3; ++i){
          int c = vt + (i<<8);
          acc = fmaf(wjh2[i], h1buf[cur^1][(c < PRED_H) ? c : 0], acc);
        }
        acc = wave_red(acc);
        if (lane == 0) zjs2[wave] = acc;
      }
      __syncthreads();
      if (tid == 0){
        float v0 = zjs[0]+zjs[1]+zjs[2]+zjs[3] + bjr[0];
        tstore(&hidT[jb],   v0 > 0.f ? v0 : 0.f, tag);
        float v1 = zjs[4]+zjs[5]+zjs[6]+zjs[7] + bjr[1];
        tstore(&hidT[jb+1], v1 > 0.f ? v1 : 0.f, tag);
        if (nj == 3){
          float v2 = zjs2[0]+zjs2[1]+zjs2[2]+zjs2[3] + bjr[2];
          tstore(&hidT[jb+2], v2 > 0.f ? v2 : 0.f, tag);
        }
      }
    }

    // ===== D: logits + argmax (parts all-gather) =====
    int k;
    {
      if (wave < 2) poll5(hidT, hidsh, tag, tid);           // hid
      __syncthreads();
      float accA = 0.f, accB = 0.f;
      #pragma unroll
      for (int i = 0; i < 10; ++i){
        float h = hidsh[lane+(i<<6)];
        accA = fmaf(wj2A[i], h, accA);
        accB = fmaf(wj2B[i], h, accB);
      }
      accA = wave_red(accA);
      accB = wave_red(accB);
      if (lane == 0){
        float lgA = accA + bjA2, lgB = accB + bjB2;
        out[(size_t)s*VOCAB + rA2] = lgA;
        out[(size_t)s*VOCAB + rB2] = lgB;
        u64 eA = mkentry(lgA, rA2, tag), eB = mkentry(lgB, rB2, tag);
        psh[wave] = eA > eB ? eA : eB;
      }
      __syncthreads();
      if (tid == 0){
        u64 m = psh[0];
        #pragma unroll
        for (int w = 1; w < 8; ++w) if (psh[w] > m) m = psh[w];
        __hip_atomic_store(&parts[wg], m, RLX, AGT);
      }
      // all-WG gather of 256 partials, local reduce
      u64 myp = 0;
      if (tid < 256){
        for(;;){
          u64 e = __hip_atomic_load(&parts[tid], RLX, AGT);
          if ((unsigned)((e>>12) & 0xFFFu) == (tag & 0xFFFu)){ myp = e; break; }
          __builtin_amdgcn_s_sleep(1);
        }
      }
      if (wave < 4){
        #pragma unroll
        for (int off = 32; off; off >>= 1){
          u64 o = __shfl_xor(myp, off, 64);
          if (o > myp) myp = o;
        }
        if (lane == 0) pmx[wave] = myp;
      }
      __syncthreads();
      u64 m = pmx[0];
      if (pmx[1] > m) m = pmx[1];
      if (pmx[2] > m) m = pmx[2];
      if (pmx[3] > m) m = pmx[3];
      k = 4095 - (int)(m & 0xFFFull);
    }

    // ===== E: decision (replicated in every WG) =====
    bool stop = (k == 0) || (sa >= MAX_SYM);
    if (!stop){
      if (wg == 0 && tid == 0) out[(size_t)NSTEPS*VOCAB + cnt] = (float)k;
      if (tid < nj){ c0c[tid] = c0p[tid]; c1c[tid] = c1p[tid]; }
      cnt++; sa++; last = k; cur ^= 1; reuse = false;
    } else {
      sa = 0; t++; reuse = true;
      if (t >= timesteps) done = true;
    }
    __syncthreads();
  }

  // labels tail (-1) and cnt
  size_t lab = (size_t)NSTEPS*VOCAB;
  int gidx = wg*NTHR + tid;
  for (int i = cnt + gidx; i < NSTEPS; i += NWG*NTHR) out[lab + i] = -1.f;
  if (wg == 0 && tid == 0) out[lab + NSTEPS] = (float)cnt;
}

extern "C" void kernel_launch(void* const* d_in, const int* in_sizes, int n_in,
                              void* d_out, int out_size, void* d_ws, size_t ws_size,
                              hipStream_t stream) {
  const float* enc  = (const float*)d_in[0];
  const int*   olen = (const int*)  d_in[1];
  const float* emb  = (const float*)d_in[2];
  const float* Wih0 = (const float*)d_in[3];
  const float* Whh0 = (const float*)d_in[4];
  const float* b0   = (const float*)d_in[5];
  const float* Wih1 = (const float*)d_in[6];
  const float* Whh1 = (const float*)d_in[7];
  const float* b1   = (const float*)d_in[8];
  const float* Wj1  = (const float*)d_in[9];
  const float* bj1  = (const float*)d_in[10];
  const float* Wj2  = (const float*)d_in[11];
  const float* bj2  = (const float*)d_in[12];
  float* out = (float*)d_out;

  u64* parts = (u64*)d_ws;
  u64* bufsT = (u64*)((char*)d_ws + 4096);
  u64* hidT  = (u64*)((char*)d_ws + 14336);

  init_ws<<<1, 256, 0, stream>>>((unsigned*)d_ws);

  void* args[] = {&enc,&olen,&emb,&Wih0,&Whh0,&b0,&Wih1,&Whh1,&b1,
                  &Wj1,&bj1,&Wj2,&bj2,&out,&parts,&bufsT,&hidT};
  hipLaunchCooperativeKernel((const void*)rnnt_decode, dim3(NWG), dim3(NTHR),
                             args, 0, stream);
}